// Round 10
// baseline (144.156 us; speedup 1.0000x reference)
//
#include <hip/hip_runtime.h>

// CRF-RNN mean-field, fully fused persistent kernel with LLC-coherent
// (sc1) cross-block communication -- NO bulk L2 wb/inv fences.
// Grid 24(z) x 24(y) x 16(x), N=9216, C=2, 5 iterations.
//
// Math (identical to R9, absmax 0.0):
//   Ks (theta=3) = Gz (x) Gy (x) Gx; Kb = S160 * E_i E_j * exp(I3_i I3_j),
//   Taylor NT=5. 6 iter pairs: pair0=(q0,q1) th3; pair(1+t)=(Pt q0,Pt q1)
//   th160. 3 norm pairs th160, filtered once; inv_nb kept in registers.
//
// Sync design (lesson R3): __threadfence (agent release/acquire) emits bulk
// L2 writeback+invalidate => ~19us/barrier + cold-L2 refetch storm. Instead
// ALL cross-block data moves via __hip_atomic_load/store RELAXED AGENT
// (global_load/store sc1: per-access LLC-coherent, bypasses stale L2/L1).
// Barrier = __syncthreads (drains vmcnt => sc1 stores at coherence point)
// + relaxed atomic counter + relaxed poll. 10 barriers, 144 co-resident
// blocks (<= 256 CUs, 7KB LDS, low VGPR).
// R7 lesson respected: z-conv = 24 strided loads/thread max.

#define DD 24
#define HH 24
#define WW 16
#define SLICE 384
#define NPTS 9216
#define NT 5
#define NPAIR 6
#define NB (DD * NPAIR)      // 144 blocks
#define LOG2E 1.4426950408889634f
#define K3L   (LOG2E / 18.0f)
#define K160L (LOG2E / 51200.0f)
#define EXP2  __builtin_amdgcn_exp2f

static __device__ __forceinline__ int iabs(int a) { return a < 0 ? -a : a; }

// ---- LLC-coherent accessors (compile to global_load/store ... sc1) ------
static __device__ __forceinline__ float2 ldc2(const float2* p) {
    unsigned long long v = __hip_atomic_load((unsigned long long*)p,
                               __ATOMIC_RELAXED, __HIP_MEMORY_SCOPE_AGENT);
    float2 f;
    __builtin_memcpy(&f, &v, 8);
    return f;
}
static __device__ __forceinline__ void stc2(float2* p, float2 f) {
    unsigned long long v;
    __builtin_memcpy(&v, &f, 8);
    __hip_atomic_store((unsigned long long*)p, v,
                       __ATOMIC_RELAXED, __HIP_MEMORY_SCOPE_AGENT);
}

// ---- grid barrier: no fences, counter-only ------------------------------
static __device__ __forceinline__ void gbar(unsigned* bar, int ph) {
    __syncthreads();   // drains vmcnt(0): our sc1 stores are LLC-visible
    if (threadIdx.x == 0) {
        __builtin_amdgcn_s_waitcnt(0);
        __hip_atomic_fetch_add(&bar[ph], 1u, __ATOMIC_RELAXED,
                               __HIP_MEMORY_SCOPE_AGENT);
        while (__hip_atomic_load(&bar[ph], __ATOMIC_RELAXED,
                                 __HIP_MEMORY_SCOPE_AGENT) < (unsigned)NB)
            __builtin_amdgcn_s_sleep(2);
    }
    __syncthreads();
}

__global__ void k_init(unsigned* bar) {
    if (threadIdx.x < 16) bar[threadIdx.x] = 0u;
}

// ---- xy separable conv of one float2 pair (block-uniform, syncs) --------
static __device__ void xyconv(float2 v, int y, int x, const float* gk,
                              float2 (*sA)[WW + 1], float2 (*sB)[WW + 1],
                              float2* ov) {
    sA[y][x] = v;
    __syncthreads();
    float a0 = 0.f, a1 = 0.f;
#pragma unroll
    for (int xp = 0; xp < WW; ++xp) {
        float w = gk[iabs(x - xp)];
        float2 vv = sA[y][xp];
        a0 = fmaf(w, vv.x, a0);
        a1 = fmaf(w, vv.y, a1);
    }
    sB[y][x] = make_float2(a0, a1);
    __syncthreads();
    float b0 = 0.f, b1 = 0.f;
#pragma unroll
    for (int yp = 0; yp < HH; ++yp) {
        float w = gk[iabs(y - yp)];
        float2 vv = sB[yp][x];
        b0 = fmaf(w, vv.x, b0);
        b1 = fmaf(w, vv.y, b1);
    }
    *ov = make_float2(b0, b1);
    __syncthreads();
}

__global__ __launch_bounds__(SLICE, 1)
void crf_fused(const float2* __restrict__ u2, const float* __restrict__ rgb,
               const float* __restrict__ sw, const float* __restrict__ bw,
               const float* __restrict__ compat,
               float2* __restrict__ tmp, float2* __restrict__ tmpN,
               float2* __restrict__ zout, float2* __restrict__ zoutN,
               unsigned* __restrict__ bar, float2* __restrict__ out) {
    __shared__ float gk[32];    // this block's kernel table (p0: g3, else g160)
    __shared__ float g3s[32];   // g3 (for inv_ns, all blocks)
    __shared__ float2 sA[HH][WW + 1];
    __shared__ float2 sB[HH][WW + 1];

    const int z = blockIdx.x, p = blockIdx.y, t = threadIdx.x;
    const int y = t >> 4, x = t & 15;
    const int i = z * SLICE + t;

    const float kk = (p == 0) ? K3L : K160L;
    if (t < DD) {
        gk[t] = EXP2(-(float)(t * t) * kk);
        g3s[t] = EXP2(-(float)(t * t) * K3L);
    }
    __syncthreads();

    // ---- per-thread invariants (live all 5 iterations) ----
    const float I3 = rgb[i] * (1.f / 3.f);
    float Pt[NT];
    Pt[0] = EXP2(-0.5f * LOG2E * I3 * I3);
#pragma unroll
    for (int k = 1; k < NT; ++k) Pt[k] = Pt[k - 1] * I3;
    const float2 uu = u2[i];
    const float sw0 = sw[0], sw1 = sw[1];
    const float bw0 = bw[0], bw1 = bw[1];
    const float c00 = compat[0], c01 = compat[1];
    const float c10 = compat[2], c11 = compat[3];

    float sx = 0.f, sy = 0.f, sz = 0.f;
#pragma unroll
    for (int xp = 0; xp < WW; ++xp) sx += g3s[iabs(x - xp)];
#pragma unroll
    for (int yp = 0; yp < HH; ++yp) sy += g3s[iabs(y - yp)];
#pragma unroll
    for (int zp = 0; zp < DD; ++zp) sz += g3s[iabs(z - zp)];
    const float inv_ns = 1.0f / (sx * sy * sz);
    const float invf[NT] = {1.f, 1.f, 0.5f, 1.f / 6.f, 1.f / 24.f};

    // ---- P phase: xy-conv of pair p from q=u (+ norm pair for p=1..3) ----
    {
        float2 v, ov;
        if (p == 0) v = uu;
        else { float P = Pt[p - 1]; v = make_float2(P * uu.x, P * uu.y); }
        xyconv(v, y, x, gk, sA, sB, &ov);
        stc2(&tmp[p * NPTS + i], ov);
        if (p >= 1 && p <= 3) {       // norm pair j = p-1 (theta=160 = gk)
            int j = p - 1;
            float2 nv = make_float2(Pt[2 * j], (j < 2) ? Pt[2 * j + 1] : 0.f);
            xyconv(nv, y, x, gk, sA, sB, &ov);
            stc2(&tmpN[j * NPTS + i], ov);
        }
    }
    gbar(bar, 0);

    float inv_nb = 0.f;
    for (int it = 0; it < 5; ++it) {
        // ---- Z phase: z-conv of pair p (24 coherent loads) ----
        {
            float a0 = 0.f, a1 = 0.f;
            const float2* src = tmp + p * NPTS + t;
            for (int zp = 0; zp < DD; ++zp) {
                int d = z - zp;
                float w = EXP2(-(float)(d * d) * kk);
                float2 vv = ldc2(&src[zp * SLICE]);
                a0 = fmaf(w, vv.x, a0);
                a1 = fmaf(w, vv.y, a1);
            }
            stc2(&zout[p * NPTS + z * SLICE + t], make_float2(a0, a1));
        }
        if (it == 0 && p >= 1 && p <= 3) {   // norm z-conv once
            int j = p - 1;
            float a0 = 0.f, a1 = 0.f;
            const float2* src = tmpN + j * NPTS + t;
            for (int zp = 0; zp < DD; ++zp) {
                int d = z - zp;
                float w = EXP2(-(float)(d * d) * K160L);
                float2 vv = ldc2(&src[zp * SLICE]);
                a0 = fmaf(w, vv.x, a0);
                a1 = fmaf(w, vv.y, a1);
            }
            stc2(&zoutN[j * NPTS + z * SLICE + t], make_float2(a0, a1));
        }
        gbar(bar, 1 + 2 * it);

        // ---- U phase: pointwise update (redundant across the 6 p-blocks) --
        float2 zp_[NPAIR];
#pragma unroll
        for (int k = 0; k < NPAIR; ++k) zp_[k] = ldc2(&zout[k * NPTS + i]);

        if (it == 0) {   // norm_b, kept in a register forever after
            float2 n0 = ldc2(&zoutN[0 * NPTS + i]);
            float2 n1 = ldc2(&zoutN[1 * NPTS + i]);
            float2 n2 = ldc2(&zoutN[2 * NPTS + i]);
            float nb = Pt[0] * n0.x + Pt[1] * n0.y + 0.5f * Pt[2] * n1.x
                     + (1.f / 6.f) * Pt[3] * n1.y + (1.f / 24.f) * Pt[4] * n2.x;
            inv_nb = 1.0f / nb;
        }

        float b0 = 0.f, b1 = 0.f;
#pragma unroll
        for (int k = 0; k < NT; ++k) {
            float w = Pt[k] * invf[k];
            b0 = fmaf(w, zp_[1 + k].x, b0);
            b1 = fmaf(w, zp_[1 + k].y, b1);
        }
        b0 *= inv_nb;
        b1 *= inv_nb;
        float s0 = zp_[0].x * inv_ns;
        float s1 = zp_[0].y * inv_ns;
        float m0 = s0 * sw0 + b0 * bw0;
        float m1 = s1 * sw1 + b1 * bw1;
        float p0 = fmaf(c00, m0, c01 * m1);
        float p1 = fmaf(c10, m0, c11 * m1);
        float q0 = uu.x - p0;
        float q1 = uu.y - p1;

        if (it == 4) {
            if (p == 0) out[i] = make_float2(q0, q1);  // end-of-kernel release
            break;
        }

        // ---- xy-conv of pair p of the new q -> tmp ----
        float2 v, ov;
        if (p == 0) v = make_float2(q0, q1);
        else { float P = Pt[p - 1]; v = make_float2(P * q0, P * q1); }
        xyconv(v, y, x, gk, sA, sB, &ov);
        stc2(&tmp[p * NPTS + i], ov);
        gbar(bar, 2 + 2 * it);
    }
}

extern "C" void kernel_launch(void* const* d_in, const int* in_sizes, int n_in,
                              void* d_out, int out_size, void* d_ws, size_t ws_size,
                              hipStream_t stream) {
    const float2* u2     = (const float2*)d_in[0];
    const float*  rgb    = (const float*)d_in[1];
    const float*  sw     = (const float*)d_in[2];
    const float*  bw     = (const float*)d_in[3];
    const float*  compat = (const float*)d_in[4];
    float2* out = (float2*)d_out;

    float2* ws2   = (float2*)d_ws;
    float2* tmp   = ws2;                       // 6*NPTS float2
    float2* tmpN  = ws2 + 6 * NPTS;            // 3*NPTS float2
    float2* zout  = ws2 + 9 * NPTS;            // 6*NPTS float2
    float2* zoutN = ws2 + 15 * NPTS;           // 3*NPTS float2
    unsigned* bar = (unsigned*)(ws2 + 18 * NPTS);   // 16 uints

    k_init<<<1, 64, 0, stream>>>(bar);
    crf_fused<<<dim3(DD, NPAIR), SLICE, 0, stream>>>(u2, rgb, sw, bw, compat,
                                                     tmp, tmpN, zout, zoutN,
                                                     bar, out);
}